// Round 9
// baseline (281.701 us; speedup 1.0000x reference)
//
#include <hip/hip_runtime.h>

// Problem constants: B=16, L=4096, H=8, E=64, K=64, F=2049 (rfft bins)
// Only bins m in [1,2048] matter (bin 0 excluded from top-k; out_ft uses slots 0..63).

#define NTHREADS 256

// LDS swizzle for the FFT working array: flips bits 1-3 by bits 4-6 (bijective, disjoint).
// Gives uniform 4-lanes-per-bank-pair (the b64 minimum) for all pass strides (8/64/512),
// pass-0 contiguous stores, and the +-m unpack reads.
#define ZI(i) ((i) ^ ((((i) >> 4) & 7) << 1))

__device__ inline float2 f2add(float2 a, float2 b) { return make_float2(a.x + b.x, a.y + b.y); }
__device__ inline float2 f2sub(float2 a, float2 b) { return make_float2(a.x - b.x, a.y - b.y); }
// complex mul, exactly 4 VALU (mul, fma, mul, fma)
__device__ inline float2 cmulf(float2 a, float2 b) {
    return make_float2(__builtin_fmaf(a.x, b.x, -(a.y * b.y)),
                       __builtin_fmaf(a.x, b.y,  a.y * b.x));
}

// radix-8 DIT butterfly on 8 points spaced h apart (3 stages in registers).
__device__ inline void radix8(float2& u0, float2& u1, float2& u2, float2& u3,
                              float2& u4, float2& u5, float2& u6, float2& u7,
                              float2 wA, float2 wB, float2 wC) {
    float2 t1 = cmulf(wA, u1), t3 = cmulf(wA, u3), t5 = cmulf(wA, u5), t7 = cmulf(wA, u7);
    float2 a0 = f2add(u0, t1), a1 = f2sub(u0, t1);
    float2 a2 = f2add(u2, t3), a3 = f2sub(u2, t3);
    float2 a4 = f2add(u4, t5), a5 = f2sub(u4, t5);
    float2 a6 = f2add(u6, t7), a7 = f2sub(u6, t7);
    float2 s2 = cmulf(wB, a2), s3 = cmulf(wB, a3);
    float2 s6 = cmulf(wB, a6), s7 = cmulf(wB, a7);
    float2 b0 = f2add(a0, s2), b2 = f2sub(a0, s2);
    float2 b1 = make_float2(a1.x + s3.y, a1.y - s3.x);   // a1 + (-i)s3
    float2 b3 = make_float2(a1.x - s3.y, a1.y + s3.x);   // a1 - (-i)s3
    float2 b4 = f2add(a4, s6), b6 = f2sub(a4, s6);
    float2 b5 = make_float2(a5.x + s7.y, a5.y - s7.x);
    float2 b7 = make_float2(a5.x - s7.y, a5.y + s7.x);
    const float2 C8 = make_float2(0.70710678118654752f, -0.70710678118654752f);  // e^{-i pi/4}
    float2 wC1 = cmulf(wC, C8);
    float2 r4 = cmulf(wC, b4);
    float2 r5 = cmulf(wC1, b5);
    float2 r6t = cmulf(wC, b6);  float2 r6 = make_float2(r6t.y, -r6t.x);   // -i * wC * b6
    float2 r7t = cmulf(wC1, b7); float2 r7 = make_float2(r7t.y, -r7t.x);   // e^{-3i pi/4} wC b7
    u0 = f2add(b0, r4); u4 = f2sub(b0, r4);
    u1 = f2add(b1, r5); u5 = f2sub(b1, r5);
    u2 = f2add(b2, r6); u6 = f2sub(b2, r6);
    u3 = f2add(b3, r7); u7 = f2sub(b3, r7);
}

// ---------------- table kernel: trig[k] = (cos, sin)(2*pi*k/4096), f64-accurate ----------------
__global__ void k_tables(float2* __restrict__ trig) {
    int k = blockIdx.x * blockDim.x + threadIdx.x;
    if (k < 4096) {
        double th = (6.283185307179586476925286766559 * (double)k) / 4096.0;
        trig[k] = make_float2((float)cos(th), (float)sin(th));
    }
}

// ---------------- transpose + bit-reversal: q[b,l,h,e] -> T[(b,h,eo)][p][j] (float2) -----------
__global__ __launch_bounds__(256) void k_xpose(const float* __restrict__ q,
                                               float2* __restrict__ T) {
    __shared__ float tile[256][65];  // padded (+1)

    const int tid = threadIdx.x;
    const int bi  = blockIdx.x;
    const int b   = bi >> 7;
    const int h   = (bi >> 4) & 7;
    const int c4  = bi & 15;

    const float* qb = q + ((size_t)b * 4096 * 512) + (size_t)h * 64;
    for (int f = tid; f < 4096; f += NTHREADS) {
        int t = f >> 4, e4 = f & 15;
        const float4 v = *(const float4*)(qb + (size_t)(c4 + 16 * t) * 512 + e4 * 4);
        tile[t][e4 * 4 + 0] = v.x;
        tile[t][e4 * 4 + 1] = v.y;
        tile[t][e4 * 4 + 2] = v.z;
        tile[t][e4 * 4 + 3] = v.w;
    }
    __syncthreads();

    const int wave = tid >> 6, lane = tid & 63;
    const int rl  = __brev(lane) >> 26;  // rev6(lane)
    const int r4c = __brev(c4) >> 28;    // rev4(c4)
    for (int cc = wave; cc < 32; cc += 4) {
        int eo = cc >> 2, p = cc & 3;
        int col0 = eo * 8 + 2 * p;
        float2* dst = T + ((size_t)((b * 8 + h) * 8 + eo)) * 16384 + (size_t)p * 4096
                        + (size_t)r4c * 256;
#pragma unroll
        for (int r = 0; r < 2; ++r) {
            int ta = 2 * rl + r;
            int tb = ta + 128;
            float4 o;
            o.x = tile[ta][col0]; o.y = tile[ta][col0 + 1];
            o.z = tile[tb][col0]; o.w = tile[tb][col0 + 1];
            *(float4*)(dst + 2 * (64 * r + lane)) = o;
        }
    }
}

// ---------------- FFT (4 x radix-8 passes) + spectrum store + score accumulation ----------------
// z is XOR-swizzled (ZI); twiddles come from compact per-pass triple tables (stride-3 layout
// is bijective mod 16 -> conflict-free reads; replaces the tw[j<<5]-style 16..64-way conflicts).
__global__ __launch_bounds__(256) void k_fft(const float2* __restrict__ trig,
                                             float2* __restrict__ Xout,
                                             unsigned long long* __restrict__ score) {
    __shared__ float2 z[4096];     // 32 KB (swizzled indexing)
    __shared__ float2 ctw[1752];   // 13.7 KB: [0,24) pass1, [24,216) pass2, [216,1752) pass3
    __shared__ float  eacc[2048];  // 8 KB

    const int tid = threadIdx.x;
    const int bi  = blockIdx.x;

    for (int t = tid; t < 2048; t += NTHREADS) eacc[t] = 0.f;
    // build compact twiddle triples: ctw[off + 3j + {0,1,2}] = conj(trig[j << {sA, sA-1, sA-2}])
    for (int t = tid; t < 584; t += NTHREADS) {
        int off, j, sA;
        if (t < 8)       { off = 0;   j = t;      sA = 8; }   // pass1 (st=4,  h=8,   j<8)
        else if (t < 72) { off = 24;  j = t - 8;  sA = 5; }   // pass2 (st=7,  h=64,  j<64)
        else             { off = 216; j = t - 72; sA = 2; }   // pass3 (st=10, h=512, j<512)
        float2 a = trig[j << sA], b = trig[j << (sA - 1)], c = trig[j << (sA - 2)];
        ctw[off + 3 * j + 0] = make_float2(a.x, -a.y);
        ctw[off + 3 * j + 1] = make_float2(b.x, -b.y);
        ctw[off + 3 * j + 2] = make_float2(c.x, -c.y);
    }
    __syncthreads();

    const float2 ONE = make_float2(1.0f, 0.0f);

    for (int p = 0; p < 4; ++p) {
        const float2* plane = Xout + (size_t)bi * 16384 + (size_t)p * 4096;

        // pass 0 (stages 1-3, h=1, unit twiddles -> constant-folded):
        for (int t = tid; t < 512; t += NTHREADS) {
            const float4 v01 = *(const float4*)(plane + 8 * t);
            const float4 v23 = *(const float4*)(plane + 8 * t + 2);
            const float4 v45 = *(const float4*)(plane + 8 * t + 4);
            const float4 v67 = *(const float4*)(plane + 8 * t + 6);
            float2 u0 = make_float2(v01.x, v01.y), u1 = make_float2(v01.z, v01.w);
            float2 u2 = make_float2(v23.x, v23.y), u3 = make_float2(v23.z, v23.w);
            float2 u4 = make_float2(v45.x, v45.y), u5 = make_float2(v45.z, v45.w);
            float2 u6 = make_float2(v67.x, v67.y), u7 = make_float2(v67.z, v67.w);
            radix8(u0, u1, u2, u3, u4, u5, u6, u7, ONE, ONE, ONE);
            const int i0 = 8 * t;
            z[ZI(i0 + 0)] = u0; z[ZI(i0 + 1)] = u1; z[ZI(i0 + 2)] = u2; z[ZI(i0 + 3)] = u3;
            z[ZI(i0 + 4)] = u4; z[ZI(i0 + 5)] = u5; z[ZI(i0 + 6)] = u6; z[ZI(i0 + 7)] = u7;
        }
        __syncthreads();

        // passes 1..3: stages (4,5,6), (7,8,9), (10,11,12); h = 8, 64, 512
#pragma unroll
        for (int p8 = 1; p8 <= 3; ++p8) {
            const int st  = 1 + 3 * p8;
            const int h   = 1 << (st - 1);
            const int off = (p8 == 1) ? 0 : (p8 == 2) ? 24 : 216;
            for (int t = tid; t < 512; t += NTHREADS) {
                const int j = t & (h - 1);
                const int g = t >> (st - 1);
                const int i0 = (g << (st + 2)) + j;
                int a0 = ZI(i0),         a1 = ZI(i0 + h),     a2 = ZI(i0 + 2 * h), a3 = ZI(i0 + 3 * h);
                int a4 = ZI(i0 + 4 * h), a5 = ZI(i0 + 5 * h), a6 = ZI(i0 + 6 * h), a7 = ZI(i0 + 7 * h);
                float2 u0 = z[a0], u1 = z[a1], u2 = z[a2], u3 = z[a3];
                float2 u4 = z[a4], u5 = z[a5], u6 = z[a6], u7 = z[a7];
                const float2 wA = ctw[off + 3 * j + 0];
                const float2 wB = ctw[off + 3 * j + 1];
                const float2 wC = ctw[off + 3 * j + 2];
                radix8(u0, u1, u2, u3, u4, u5, u6, u7, wA, wB, wC);
                z[a0] = u0; z[a1] = u1; z[a2] = u2; z[a3] = u3;
                z[a4] = u4; z[a5] = u5; z[a6] = u6; z[a7] = u7;
            }
            __syncthreads();
        }

        // unpack two real spectra; store (overwrites this pair's own plane); accumulate energy
        {
            const size_t s0 = (size_t)bi * 16384 + (size_t)p * 4096;  // = signal (bi*8+2p) * 2048
            for (int t = tid; t < 2048; t += NTHREADS) {
                int m = t + 1;
                float2 Za = z[ZI(m)];
                float2 Zb = z[ZI(4096 - m)];
                float Xr0 = 0.5f * (Za.x + Zb.x);
                float Xi0 = 0.5f * (Za.y - Zb.y);
                float Xr1 = 0.5f * (Za.y + Zb.y);
                float Xi1 = 0.5f * (Zb.x - Za.x);
                Xout[s0 + t]        = make_float2(Xr0, Xi0);
                Xout[s0 + 2048 + t] = make_float2(Xr1, Xi1);
                eacc[t] += Xr0 * Xr0 + Xi0 * Xi0 + Xr1 * Xr1 + Xi1 * Xi1;
            }
        }
        __syncthreads();  // protect z before next pair's load
    }

    // deterministic reduction: fixed-point u64 atomics (integer adds commute exactly)
    for (int t = tid; t < 2048; t += NTHREADS) {
        unsigned long long v = (unsigned long long)llrintf(eacc[t] * 1048576.0f);  // 2^20
        atomicAdd(&score[t], v);
    }
}

// ---------------- top-64, parallelized: 8 blocks x 256 threads, one candidate per thread -------
__global__ __launch_bounds__(256) void k_topk(const unsigned long long* __restrict__ score,
                                              int* __restrict__ idx) {
    __shared__ unsigned long long s[2048];
    const int tid = threadIdx.x;
    for (int t = tid; t < 2048; t += 256) s[t] = score[t];
    __syncthreads();

    const int t = blockIdx.x * 256 + tid;  // 0..2047
    const unsigned long long my = s[t];
    int rank = 0;
#pragma unroll 8
    for (int u = 0; u < 2048; ++u) {
        unsigned long long o = s[u];
        rank += (int)((o > my) || (o == my && u < t));
    }
    if (rank < 64) idx[rank] = t + 1;  // store frequency index m
}

// ---------------- gather + complex projection: Y[b,j,h,f] = sum_e X[b,idx_j,h,e] * W[j,h,e,f] ----
__global__ __launch_bounds__(256) void k_proj(const float2* __restrict__ X,
                                              const float* __restrict__ wr,
                                              const float* __restrict__ wi,
                                              const int* __restrict__ idx,
                                              float2* __restrict__ Y) {
    __shared__ float2 xs[16 * 64];   // [b][e]  8 KB
    __shared__ float  wrs[64 * 64];  // [e][f] 16 KB
    __shared__ float  wis[64 * 64];  // 16 KB

    const int tid = threadIdx.x;
    const int j = blockIdx.x >> 3;
    const int h = blockIdx.x & 7;
    const int m = idx[j];

    for (int t = tid; t < 1024; t += NTHREADS) {
        int b = t >> 6, e = t & 63;
        xs[t] = X[((size_t)((b * 8 + h) * 64 + e)) * 2048 + (size_t)(m - 1)];
    }
    const float* wrb = wr + ((size_t)(j * 8 + h)) * 4096;
    const float* wib = wi + ((size_t)(j * 8 + h)) * 4096;
    for (int t = tid; t < 4096; t += NTHREADS) { wrs[t] = wrb[t]; wis[t] = wib[t]; }
    __syncthreads();

    const int b  = tid >> 4;   // 0..15
    const int fg = tid & 15;   // 0..15
    for (int fo = 0; fo < 4; ++fo) {
        int f = fg * 4 + fo;
        float yr = 0.f, yi = 0.f;
        for (int e = 0; e < 64; ++e) {
            float2 x = xs[b * 64 + e];
            float a = wrs[e * 64 + f], c = wis[e * 64 + f];
            yr = __builtin_fmaf(x.x, a, yr); yr = __builtin_fmaf(-x.y, c, yr);
            yi = __builtin_fmaf(x.x, c, yi); yi = __builtin_fmaf( x.y, a, yi);
        }
        Y[((size_t)b * 64 + j) * 512 + (size_t)(h * 64 + f)] = make_float2(yr, yi);
    }
}

// ---------------- synthesis with full w-symmetry: 1 rotator -> 4 output rows -------------------
//   out(l)      = F0+F1+F2+F3          out(l+2048) = F0-F1+F2-F3
//   out(l+1024) = (F0-F2)-(H1-H3)      out(l+3072) = (F0-F2)+(H1-H3)
__global__ __launch_bounds__(256, 2) void k_synth(const float2* __restrict__ Y,
                                                  const float2* __restrict__ trig,
                                                  float* __restrict__ out) {
    __shared__ float2 ys[64][64];  // 32 KB, pre-scaled: j=0 -> (Yr/N, 0); j>0 -> (2/N)*Y

    const int tid = threadIdx.x;
    const int bi  = blockIdx.x;
    const int b   = bi >> 7;        // 16
    const int hft = (bi >> 4) & 7;  // 8
    const int lt  = bi & 15;        // 16

    const float invN = 1.0f / 4096.0f;
    const float2* yb = Y + (size_t)b * 64 * 512 + (size_t)hft * 64;
    for (int t = tid; t < 64 * 64; t += NTHREADS) {
        int j = t >> 6, cc = t & 63;
        float2 y = yb[(size_t)j * 512 + cc];
        if (j == 0) ys[0][cc] = make_float2(y.x * invN, 0.0f);
        else        ys[j][cc] = make_float2(y.x * (2.0f * invN), y.y * (2.0f * invN));
    }
    __syncthreads();

    const int r = tid >> 3;          // 0..31
    const int c = tid & 7;           // 0..7
    const int l0 = lt * 64 + r * 2;  // base l (v=0) in [0, 1024)

    float2 rot[2], w[2];
#pragma unroll
    for (int v = 0; v < 2; ++v) {
        w[v] = trig[(l0 + v) & 4095];
        rot[v] = make_float2(1.0f, 0.0f);
    }

    float F0[2][8], F1[2][8], F2[2][8], F3[2][8], H1[2][8], H3[2][8];
#pragma unroll
    for (int v = 0; v < 2; ++v)
#pragma unroll
        for (int u = 0; u < 8; ++u) {
            F0[v][u] = F1[v][u] = F2[v][u] = F3[v][u] = 0.0f;
            H1[v][u] = H3[v][u] = 0.0f;
        }

    for (int j = 0; j < 64; j += 4) {
        // j+0 (even) -> F0
        {
            float2 yv[8];
#pragma unroll
            for (int u = 0; u < 8; ++u) yv[u] = ys[j][c * 2 + (u & 1) + (u >> 1) * 16];
#pragma unroll
            for (int v = 0; v < 2; ++v) {
                const float cx = rot[v].x, sx = rot[v].y;
#pragma unroll
                for (int u = 0; u < 8; ++u) {
                    float a = F0[v][u];
                    a = __builtin_fmaf(cx, yv[u].x, a);
                    a = __builtin_fmaf(-sx, yv[u].y, a);
                    F0[v][u] = a;
                }
                float nx = __builtin_fmaf(rot[v].x, w[v].x, -(rot[v].y * w[v].y));
                float ny = __builtin_fmaf(rot[v].x, w[v].y,  (rot[v].y * w[v].x));
                rot[v] = make_float2(nx, ny);
            }
        }
        // j+1 (odd) -> F1, H1
        {
            float2 yv[8];
#pragma unroll
            for (int u = 0; u < 8; ++u) yv[u] = ys[j + 1][c * 2 + (u & 1) + (u >> 1) * 16];
#pragma unroll
            for (int v = 0; v < 2; ++v) {
                const float cx = rot[v].x, sx = rot[v].y;
#pragma unroll
                for (int u = 0; u < 8; ++u) {
                    float a = F1[v][u], g = H1[v][u];
                    a = __builtin_fmaf(cx, yv[u].x, a);
                    a = __builtin_fmaf(-sx, yv[u].y, a);
                    g = __builtin_fmaf(sx, yv[u].x, g);
                    g = __builtin_fmaf(cx, yv[u].y, g);
                    F1[v][u] = a; H1[v][u] = g;
                }
                float nx = __builtin_fmaf(rot[v].x, w[v].x, -(rot[v].y * w[v].y));
                float ny = __builtin_fmaf(rot[v].x, w[v].y,  (rot[v].y * w[v].x));
                rot[v] = make_float2(nx, ny);
            }
        }
        // j+2 (even) -> F2
        {
            float2 yv[8];
#pragma unroll
            for (int u = 0; u < 8; ++u) yv[u] = ys[j + 2][c * 2 + (u & 1) + (u >> 1) * 16];
#pragma unroll
            for (int v = 0; v < 2; ++v) {
                const float cx = rot[v].x, sx = rot[v].y;
#pragma unroll
                for (int u = 0; u < 8; ++u) {
                    float a = F2[v][u];
                    a = __builtin_fmaf(cx, yv[u].x, a);
                    a = __builtin_fmaf(-sx, yv[u].y, a);
                    F2[v][u] = a;
                }
                float nx = __builtin_fmaf(rot[v].x, w[v].x, -(rot[v].y * w[v].y));
                float ny = __builtin_fmaf(rot[v].x, w[v].y,  (rot[v].y * w[v].x));
                rot[v] = make_float2(nx, ny);
            }
        }
        // j+3 (odd) -> F3, H3
        {
            float2 yv[8];
#pragma unroll
            for (int u = 0; u < 8; ++u) yv[u] = ys[j + 3][c * 2 + (u & 1) + (u >> 1) * 16];
#pragma unroll
            for (int v = 0; v < 2; ++v) {
                const float cx = rot[v].x, sx = rot[v].y;
#pragma unroll
                for (int u = 0; u < 8; ++u) {
                    float a = F3[v][u], g = H3[v][u];
                    a = __builtin_fmaf(cx, yv[u].x, a);
                    a = __builtin_fmaf(-sx, yv[u].y, a);
                    g = __builtin_fmaf(sx, yv[u].x, g);
                    g = __builtin_fmaf(cx, yv[u].y, g);
                    F3[v][u] = a; H3[v][u] = g;
                }
                float nx = __builtin_fmaf(rot[v].x, w[v].x, -(rot[v].y * w[v].y));
                float ny = __builtin_fmaf(rot[v].x, w[v].y,  (rot[v].y * w[v].x));
                rot[v] = make_float2(nx, ny);
            }
        }
    }

    // stores: 4 rows per (v): l0+v, +1024, +2048, +3072
#pragma unroll
    for (int v = 0; v < 2; ++v) {
        float* o0 = out + ((size_t)(b * 4096 + l0 + v)) * 512 + (size_t)hft * 64;
        float* o1 = o0 + (size_t)1024 * 512;
        float* o2 = o0 + (size_t)2048 * 512;
        float* o3 = o0 + (size_t)3072 * 512;
#pragma unroll
        for (int k = 0; k < 4; ++k) {
            float2 s0, s1, s2, s3;
#pragma unroll
            for (int d = 0; d < 2; ++d) {
                const int u = 2 * k + d;
                const float p = F0[v][u] + F2[v][u];
                const float m = F0[v][u] - F2[v][u];
                const float q = F1[v][u] + F3[v][u];
                const float hh = H3[v][u] - H1[v][u];
                ((float*)&s0)[d] = p + q;
                ((float*)&s2)[d] = p - q;
                ((float*)&s1)[d] = m + hh;
                ((float*)&s3)[d] = m - hh;
            }
            *(float2*)(o0 + k * 16 + c * 2) = s0;
            *(float2*)(o1 + k * 16 + c * 2) = s1;
            *(float2*)(o2 + k * 16 + c * 2) = s2;
            *(float2*)(o3 + k * 16 + c * 2) = s3;
        }
    }
}

// ---------------- launch ----------------
extern "C" void kernel_launch(void* const* d_in, const int* in_sizes, int n_in,
                              void* d_out, int out_size, void* d_ws, size_t ws_size,
                              hipStream_t stream) {
    const float* q  = (const float*)d_in[0];
    const float* wr = (const float*)d_in[3];
    const float* wi = (const float*)d_in[4];

    char* ws = (char*)d_ws;
    float2*             trig  = (float2*)(ws + 0);                  // 32 KB
    unsigned long long* score = (unsigned long long*)(ws + 32768);  // 16 KB
    int*                idx   = (int*)(ws + 49152);                 // 256 B
    float2*             Y     = (float2*)(ws + 65536);              // 4 MB

    // d_out triples as: transposed-q scratch T -> spectrum Xout (in-place) -> final output.
    float2* Xs = (float2*)d_out;

    hipMemsetAsync(score, 0, 2048 * sizeof(unsigned long long), stream);
    k_tables<<<16, 256, 0, stream>>>(trig);
    k_xpose<<<2048, 256, 0, stream>>>(q, Xs);          // (b:16, h:8, c4:16)
    k_fft<<<1024, 256, 0, stream>>>(trig, Xs, score);  // in-place T -> spectra
    k_topk<<<8, 256, 0, stream>>>(score, idx);         // 2048 candidates, 1/thread
    k_proj<<<512, 256, 0, stream>>>(Xs, wr, wi, idx, Y);
    k_synth<<<2048, 256, 0, stream>>>(Y, trig, (float*)d_out);  // (b:16, hft:8, lt:16)
}

// Round 10
// 273.949 us; speedup vs baseline: 1.0283x; 1.0283x over previous
//
#include <hip/hip_runtime.h>

// Problem constants: B=16, L=4096, H=8, E=64, K=64, F=2049 (rfft bins)
// Only bins m in [1,2048] matter (bin 0 excluded from top-k; out_ft uses slots 0..63).

#define NTHREADS 256

// LDS swizzle for the FFT working array: flips bits 1-3 by bits 4-6 (bijective, disjoint).
#define ZI(i) ((i) ^ ((((i) >> 4) & 7) << 1))

__device__ inline float2 f2add(float2 a, float2 b) { return make_float2(a.x + b.x, a.y + b.y); }
__device__ inline float2 f2sub(float2 a, float2 b) { return make_float2(a.x - b.x, a.y - b.y); }
// complex mul, exactly 4 VALU (mul, fma, mul, fma)
__device__ inline float2 cmulf(float2 a, float2 b) {
    return make_float2(__builtin_fmaf(a.x, b.x, -(a.y * b.y)),
                       __builtin_fmaf(a.x, b.y,  a.y * b.x));
}

// radix-8 DIT butterfly on 8 points (3 stages in registers).
__device__ inline void radix8(float2& u0, float2& u1, float2& u2, float2& u3,
                              float2& u4, float2& u5, float2& u6, float2& u7,
                              float2 wA, float2 wB, float2 wC) {
    float2 t1 = cmulf(wA, u1), t3 = cmulf(wA, u3), t5 = cmulf(wA, u5), t7 = cmulf(wA, u7);
    float2 a0 = f2add(u0, t1), a1 = f2sub(u0, t1);
    float2 a2 = f2add(u2, t3), a3 = f2sub(u2, t3);
    float2 a4 = f2add(u4, t5), a5 = f2sub(u4, t5);
    float2 a6 = f2add(u6, t7), a7 = f2sub(u6, t7);
    float2 s2 = cmulf(wB, a2), s3 = cmulf(wB, a3);
    float2 s6 = cmulf(wB, a6), s7 = cmulf(wB, a7);
    float2 b0 = f2add(a0, s2), b2 = f2sub(a0, s2);
    float2 b1 = make_float2(a1.x + s3.y, a1.y - s3.x);   // a1 + (-i)s3
    float2 b3 = make_float2(a1.x - s3.y, a1.y + s3.x);   // a1 - (-i)s3
    float2 b4 = f2add(a4, s6), b6 = f2sub(a4, s6);
    float2 b5 = make_float2(a5.x + s7.y, a5.y - s7.x);
    float2 b7 = make_float2(a5.x - s7.y, a5.y + s7.x);
    const float2 C8 = make_float2(0.70710678118654752f, -0.70710678118654752f);  // e^{-i pi/4}
    float2 wC1 = cmulf(wC, C8);
    float2 r4 = cmulf(wC, b4);
    float2 r5 = cmulf(wC1, b5);
    float2 r6t = cmulf(wC, b6);  float2 r6 = make_float2(r6t.y, -r6t.x);   // -i * wC * b6
    float2 r7t = cmulf(wC1, b7); float2 r7 = make_float2(r7t.y, -r7t.x);   // e^{-3i pi/4} wC b7
    u0 = f2add(b0, r4); u4 = f2sub(b0, r4);
    u1 = f2add(b1, r5); u5 = f2sub(b1, r5);
    u2 = f2add(b2, r6); u6 = f2sub(b2, r6);
    u3 = f2add(b3, r7); u7 = f2sub(b3, r7);
}

// ---------------- table kernel: trig[k] = (cos, sin)(2*pi*k/4096), f64-accurate ----------------
__global__ void k_tables(float2* __restrict__ trig) {
    int k = blockIdx.x * blockDim.x + threadIdx.x;
    if (k < 4096) {
        double th = (6.283185307179586476925286766559 * (double)k) / 4096.0;
        trig[k] = make_float2((float)cos(th), (float)sin(th));
    }
}

// ---------------- transpose + bit-reversal: q[b,l,h,e] -> T[(b,h,eo)][p][j] (float2) -----------
__global__ __launch_bounds__(256) void k_xpose(const float* __restrict__ q,
                                               float2* __restrict__ T) {
    __shared__ float tile[256][65];  // padded (+1)

    const int tid = threadIdx.x;
    const int bi  = blockIdx.x;
    const int b   = bi >> 7;
    const int h   = (bi >> 4) & 7;
    const int c4  = bi & 15;

    const float* qb = q + ((size_t)b * 4096 * 512) + (size_t)h * 64;
    for (int f = tid; f < 4096; f += NTHREADS) {
        int t = f >> 4, e4 = f & 15;
        const float4 v = *(const float4*)(qb + (size_t)(c4 + 16 * t) * 512 + e4 * 4);
        tile[t][e4 * 4 + 0] = v.x;
        tile[t][e4 * 4 + 1] = v.y;
        tile[t][e4 * 4 + 2] = v.z;
        tile[t][e4 * 4 + 3] = v.w;
    }
    __syncthreads();

    const int wave = tid >> 6, lane = tid & 63;
    const int rl  = __brev(lane) >> 26;  // rev6(lane)
    const int r4c = __brev(c4) >> 28;    // rev4(c4)
    for (int cc = wave; cc < 32; cc += 4) {
        int eo = cc >> 2, p = cc & 3;
        int col0 = eo * 8 + 2 * p;
        float2* dst = T + ((size_t)((b * 8 + h) * 8 + eo)) * 16384 + (size_t)p * 4096
                        + (size_t)r4c * 256;
#pragma unroll
        for (int r = 0; r < 2; ++r) {
            int ta = 2 * rl + r;
            int tb = ta + 128;
            float4 o;
            o.x = tile[ta][col0]; o.y = tile[ta][col0 + 1];
            o.z = tile[tb][col0]; o.w = tile[tb][col0 + 1];
            *(float4*)(dst + 2 * (64 * r + lane)) = o;
        }
    }
}

// ---------------- FFT (4 x radix-8 passes) + spectrum store + score accumulation ----------------
// Latency-oriented: eacc in registers (LDS 45.7KB -> 3 blocks/CU) and register prefetch of the
// next plane's inputs (HBM/L2 latency hides under passes 1-3 + unpack of the current plane).
__global__ __launch_bounds__(256) void k_fft(const float2* __restrict__ trig,
                                             float2* __restrict__ Xout,
                                             unsigned long long* __restrict__ score) {
    __shared__ float2 z[4096];     // 32 KB (swizzled indexing)
    __shared__ float2 ctw[1752];   // 13.7 KB: [0,24) pass1, [24,216) pass2, [216,1752) pass3

    const int tid = threadIdx.x;
    const int bi  = blockIdx.x;

    // build compact twiddle triples: ctw[off + 3j + {0,1,2}] = conj(trig[j << {sA, sA-1, sA-2}])
    for (int t = tid; t < 584; t += NTHREADS) {
        int off, j, sA;
        if (t < 8)       { off = 0;   j = t;      sA = 8; }   // pass1 (st=4,  h=8,   j<8)
        else if (t < 72) { off = 24;  j = t - 8;  sA = 5; }   // pass2 (st=7,  h=64,  j<64)
        else             { off = 216; j = t - 72; sA = 2; }   // pass3 (st=10, h=512, j<512)
        float2 a = trig[j << sA], b = trig[j << (sA - 1)], c = trig[j << (sA - 2)];
        ctw[off + 3 * j + 0] = make_float2(a.x, -a.y);
        ctw[off + 3 * j + 1] = make_float2(b.x, -b.y);
        ctw[off + 3 * j + 2] = make_float2(c.x, -c.y);
    }

    float eaccr[8];
#pragma unroll
    for (int k = 0; k < 8; ++k) eaccr[k] = 0.f;

    const float2 ONE = make_float2(1.0f, 0.0f);
    const float2* base = Xout + (size_t)bi * 16384;

    // prefetch plane 0 into registers (2 items/thread x 4 float4)
    float4 pre[2][4];
#pragma unroll
    for (int it = 0; it < 2; ++it) {
        const int t = tid + 256 * it;
#pragma unroll
        for (int g = 0; g < 4; ++g) pre[it][g] = *(const float4*)(base + 8 * t + 2 * g);
    }
    __syncthreads();  // ctw ready

    for (int p = 0; p < 4; ++p) {
        // move prefetched data to cur, then immediately issue next plane's loads
        float4 cur[2][4];
#pragma unroll
        for (int it = 0; it < 2; ++it)
#pragma unroll
            for (int g = 0; g < 4; ++g) cur[it][g] = pre[it][g];

        if (p < 3) {
            const float2* pn = base + (size_t)(p + 1) * 4096;
#pragma unroll
            for (int it = 0; it < 2; ++it) {
                const int t = tid + 256 * it;
#pragma unroll
                for (int g = 0; g < 4; ++g) pre[it][g] = *(const float4*)(pn + 8 * t + 2 * g);
            }
        }

        // pass 0 (stages 1-3, unit twiddles) on registers; store swizzled to LDS
#pragma unroll
        for (int it = 0; it < 2; ++it) {
            const int t = tid + 256 * it;
            float2 u0 = make_float2(cur[it][0].x, cur[it][0].y);
            float2 u1 = make_float2(cur[it][0].z, cur[it][0].w);
            float2 u2 = make_float2(cur[it][1].x, cur[it][1].y);
            float2 u3 = make_float2(cur[it][1].z, cur[it][1].w);
            float2 u4 = make_float2(cur[it][2].x, cur[it][2].y);
            float2 u5 = make_float2(cur[it][2].z, cur[it][2].w);
            float2 u6 = make_float2(cur[it][3].x, cur[it][3].y);
            float2 u7 = make_float2(cur[it][3].z, cur[it][3].w);
            radix8(u0, u1, u2, u3, u4, u5, u6, u7, ONE, ONE, ONE);
            const int i0 = 8 * t;
            z[ZI(i0 + 0)] = u0; z[ZI(i0 + 1)] = u1; z[ZI(i0 + 2)] = u2; z[ZI(i0 + 3)] = u3;
            z[ZI(i0 + 4)] = u4; z[ZI(i0 + 5)] = u5; z[ZI(i0 + 6)] = u6; z[ZI(i0 + 7)] = u7;
        }
        __syncthreads();

        // passes 1..3: stages (4,5,6), (7,8,9), (10,11,12); h = 8, 64, 512
#pragma unroll
        for (int p8 = 1; p8 <= 3; ++p8) {
            const int st  = 1 + 3 * p8;
            const int h   = 1 << (st - 1);
            const int off = (p8 == 1) ? 0 : (p8 == 2) ? 24 : 216;
            for (int t = tid; t < 512; t += NTHREADS) {
                const int j = t & (h - 1);
                const int g = t >> (st - 1);
                const int i0 = (g << (st + 2)) + j;
                int a0 = ZI(i0),         a1 = ZI(i0 + h),     a2 = ZI(i0 + 2 * h), a3 = ZI(i0 + 3 * h);
                int a4 = ZI(i0 + 4 * h), a5 = ZI(i0 + 5 * h), a6 = ZI(i0 + 6 * h), a7 = ZI(i0 + 7 * h);
                float2 u0 = z[a0], u1 = z[a1], u2 = z[a2], u3 = z[a3];
                float2 u4 = z[a4], u5 = z[a5], u6 = z[a6], u7 = z[a7];
                const float2 wA = ctw[off + 3 * j + 0];
                const float2 wB = ctw[off + 3 * j + 1];
                const float2 wC = ctw[off + 3 * j + 2];
                radix8(u0, u1, u2, u3, u4, u5, u6, u7, wA, wB, wC);
                z[a0] = u0; z[a1] = u1; z[a2] = u2; z[a3] = u3;
                z[a4] = u4; z[a5] = u5; z[a6] = u6; z[a7] = u7;
            }
            __syncthreads();
        }

        // unpack two real spectra; store (overwrites this pair's own plane); accumulate energy
        {
            const size_t s0 = (size_t)bi * 16384 + (size_t)p * 4096;  // = signal (bi*8+2p) * 2048
#pragma unroll
            for (int k = 0; k < 8; ++k) {
                const int t = tid + 256 * k;
                const int m = t + 1;
                float2 Za = z[ZI(m)];
                float2 Zb = z[ZI(4096 - m)];
                float Xr0 = 0.5f * (Za.x + Zb.x);
                float Xi0 = 0.5f * (Za.y - Zb.y);
                float Xr1 = 0.5f * (Za.y + Zb.y);
                float Xi1 = 0.5f * (Zb.x - Za.x);
                Xout[s0 + t]        = make_float2(Xr0, Xi0);
                Xout[s0 + 2048 + t] = make_float2(Xr1, Xi1);
                eaccr[k] += Xr0 * Xr0 + Xi0 * Xi0 + Xr1 * Xr1 + Xi1 * Xi1;
            }
        }
        __syncthreads();  // protect z before next plane's pass-0 stores
    }

    // deterministic reduction: fixed-point u64 atomics (integer adds commute exactly)
#pragma unroll
    for (int k = 0; k < 8; ++k) {
        unsigned long long v = (unsigned long long)llrintf(eaccr[k] * 1048576.0f);  // 2^20
        atomicAdd(&score[tid + 256 * k], v);
    }
}

// ---------------- top-64, parallelized: 8 blocks x 256 threads, one candidate per thread -------
__global__ __launch_bounds__(256) void k_topk(const unsigned long long* __restrict__ score,
                                              int* __restrict__ idx) {
    __shared__ unsigned long long s[2048];
    const int tid = threadIdx.x;
    for (int t = tid; t < 2048; t += 256) s[t] = score[t];
    __syncthreads();

    const int t = blockIdx.x * 256 + tid;  // 0..2047
    const unsigned long long my = s[t];
    int rank = 0;
#pragma unroll 8
    for (int u = 0; u < 2048; ++u) {
        unsigned long long o = s[u];
        rank += (int)((o > my) || (o == my && u < t));
    }
    if (rank < 64) idx[rank] = t + 1;  // store frequency index m
}

// ---------------- gather + complex projection: Y[b,j,h,f] = sum_e X[b,idx_j,h,e] * W[j,h,e,f] ----
__global__ __launch_bounds__(256) void k_proj(const float2* __restrict__ X,
                                              const float* __restrict__ wr,
                                              const float* __restrict__ wi,
                                              const int* __restrict__ idx,
                                              float2* __restrict__ Y) {
    __shared__ float2 xs[16 * 64];   // [b][e]  8 KB
    __shared__ float  wrs[64 * 64];  // [e][f] 16 KB
    __shared__ float  wis[64 * 64];  // 16 KB

    const int tid = threadIdx.x;
    const int j = blockIdx.x >> 3;
    const int h = blockIdx.x & 7;
    const int m = idx[j];

    for (int t = tid; t < 1024; t += NTHREADS) {
        int b = t >> 6, e = t & 63;
        xs[t] = X[((size_t)((b * 8 + h) * 64 + e)) * 2048 + (size_t)(m - 1)];
    }
    const float* wrb = wr + ((size_t)(j * 8 + h)) * 4096;
    const float* wib = wi + ((size_t)(j * 8 + h)) * 4096;
    for (int t = tid; t < 4096; t += NTHREADS) { wrs[t] = wrb[t]; wis[t] = wib[t]; }
    __syncthreads();

    const int b  = tid >> 4;   // 0..15
    const int fg = tid & 15;   // 0..15
    for (int fo = 0; fo < 4; ++fo) {
        int f = fg * 4 + fo;
        float yr = 0.f, yi = 0.f;
        for (int e = 0; e < 64; ++e) {
            float2 x = xs[b * 64 + e];
            float a = wrs[e * 64 + f], c = wis[e * 64 + f];
            yr = __builtin_fmaf(x.x, a, yr); yr = __builtin_fmaf(-x.y, c, yr);
            yi = __builtin_fmaf(x.x, c, yi); yi = __builtin_fmaf( x.y, a, yi);
        }
        Y[((size_t)b * 64 + j) * 512 + (size_t)(h * 64 + f)] = make_float2(yr, yi);
    }
}

// ---------------- synthesis with full w-symmetry: 1 rotator -> 4 output rows -------------------
//   out(l)      = F0+F1+F2+F3          out(l+2048) = F0-F1+F2-F3
//   out(l+1024) = (F0-F2)-(H1-H3)      out(l+3072) = (F0-F2)+(H1-H3)
__global__ __launch_bounds__(256, 2) void k_synth(const float2* __restrict__ Y,
                                                  const float2* __restrict__ trig,
                                                  float* __restrict__ out) {
    __shared__ float2 ys[64][64];  // 32 KB, pre-scaled: j=0 -> (Yr/N, 0); j>0 -> (2/N)*Y

    const int tid = threadIdx.x;
    const int bi  = blockIdx.x;
    const int b   = bi >> 7;        // 16
    const int hft = (bi >> 4) & 7;  // 8
    const int lt  = bi & 15;        // 16

    const float invN = 1.0f / 4096.0f;
    const float2* yb = Y + (size_t)b * 64 * 512 + (size_t)hft * 64;
    for (int t = tid; t < 64 * 64; t += NTHREADS) {
        int j = t >> 6, cc = t & 63;
        float2 y = yb[(size_t)j * 512 + cc];
        if (j == 0) ys[0][cc] = make_float2(y.x * invN, 0.0f);
        else        ys[j][cc] = make_float2(y.x * (2.0f * invN), y.y * (2.0f * invN));
    }
    __syncthreads();

    const int r = tid >> 3;          // 0..31
    const int c = tid & 7;           // 0..7
    const int l0 = lt * 64 + r * 2;  // base l (v=0) in [0, 1024)

    float2 rot[2], w[2];
#pragma unroll
    for (int v = 0; v < 2; ++v) {
        w[v] = trig[(l0 + v) & 4095];
        rot[v] = make_float2(1.0f, 0.0f);
    }

    float F0[2][8], F1[2][8], F2[2][8], F3[2][8], H1[2][8], H3[2][8];
#pragma unroll
    for (int v = 0; v < 2; ++v)
#pragma unroll
        for (int u = 0; u < 8; ++u) {
            F0[v][u] = F1[v][u] = F2[v][u] = F3[v][u] = 0.0f;
            H1[v][u] = H3[v][u] = 0.0f;
        }

    for (int j = 0; j < 64; j += 4) {
        // j+0 (even) -> F0
        {
            float2 yv[8];
#pragma unroll
            for (int u = 0; u < 8; ++u) yv[u] = ys[j][c * 2 + (u & 1) + (u >> 1) * 16];
#pragma unroll
            for (int v = 0; v < 2; ++v) {
                const float cx = rot[v].x, sx = rot[v].y;
#pragma unroll
                for (int u = 0; u < 8; ++u) {
                    float a = F0[v][u];
                    a = __builtin_fmaf(cx, yv[u].x, a);
                    a = __builtin_fmaf(-sx, yv[u].y, a);
                    F0[v][u] = a;
                }
                float nx = __builtin_fmaf(rot[v].x, w[v].x, -(rot[v].y * w[v].y));
                float ny = __builtin_fmaf(rot[v].x, w[v].y,  (rot[v].y * w[v].x));
                rot[v] = make_float2(nx, ny);
            }
        }
        // j+1 (odd) -> F1, H1
        {
            float2 yv[8];
#pragma unroll
            for (int u = 0; u < 8; ++u) yv[u] = ys[j + 1][c * 2 + (u & 1) + (u >> 1) * 16];
#pragma unroll
            for (int v = 0; v < 2; ++v) {
                const float cx = rot[v].x, sx = rot[v].y;
#pragma unroll
                for (int u = 0; u < 8; ++u) {
                    float a = F1[v][u], g = H1[v][u];
                    a = __builtin_fmaf(cx, yv[u].x, a);
                    a = __builtin_fmaf(-sx, yv[u].y, a);
                    g = __builtin_fmaf(sx, yv[u].x, g);
                    g = __builtin_fmaf(cx, yv[u].y, g);
                    F1[v][u] = a; H1[v][u] = g;
                }
                float nx = __builtin_fmaf(rot[v].x, w[v].x, -(rot[v].y * w[v].y));
                float ny = __builtin_fmaf(rot[v].x, w[v].y,  (rot[v].y * w[v].x));
                rot[v] = make_float2(nx, ny);
            }
        }
        // j+2 (even) -> F2
        {
            float2 yv[8];
#pragma unroll
            for (int u = 0; u < 8; ++u) yv[u] = ys[j + 2][c * 2 + (u & 1) + (u >> 1) * 16];
#pragma unroll
            for (int v = 0; v < 2; ++v) {
                const float cx = rot[v].x, sx = rot[v].y;
#pragma unroll
                for (int u = 0; u < 8; ++u) {
                    float a = F2[v][u];
                    a = __builtin_fmaf(cx, yv[u].x, a);
                    a = __builtin_fmaf(-sx, yv[u].y, a);
                    F2[v][u] = a;
                }
                float nx = __builtin_fmaf(rot[v].x, w[v].x, -(rot[v].y * w[v].y));
                float ny = __builtin_fmaf(rot[v].x, w[v].y,  (rot[v].y * w[v].x));
                rot[v] = make_float2(nx, ny);
            }
        }
        // j+3 (odd) -> F3, H3
        {
            float2 yv[8];
#pragma unroll
            for (int u = 0; u < 8; ++u) yv[u] = ys[j + 3][c * 2 + (u & 1) + (u >> 1) * 16];
#pragma unroll
            for (int v = 0; v < 2; ++v) {
                const float cx = rot[v].x, sx = rot[v].y;
#pragma unroll
                for (int u = 0; u < 8; ++u) {
                    float a = F3[v][u], g = H3[v][u];
                    a = __builtin_fmaf(cx, yv[u].x, a);
                    a = __builtin_fmaf(-sx, yv[u].y, a);
                    g = __builtin_fmaf(sx, yv[u].x, g);
                    g = __builtin_fmaf(cx, yv[u].y, g);
                    F3[v][u] = a; H3[v][u] = g;
                }
                float nx = __builtin_fmaf(rot[v].x, w[v].x, -(rot[v].y * w[v].y));
                float ny = __builtin_fmaf(rot[v].x, w[v].y,  (rot[v].y * w[v].x));
                rot[v] = make_float2(nx, ny);
            }
        }
    }

    // stores: 4 rows per (v): l0+v, +1024, +2048, +3072
#pragma unroll
    for (int v = 0; v < 2; ++v) {
        float* o0 = out + ((size_t)(b * 4096 + l0 + v)) * 512 + (size_t)hft * 64;
        float* o1 = o0 + (size_t)1024 * 512;
        float* o2 = o0 + (size_t)2048 * 512;
        float* o3 = o0 + (size_t)3072 * 512;
#pragma unroll
        for (int k = 0; k < 4; ++k) {
            float2 s0, s1, s2, s3;
#pragma unroll
            for (int d = 0; d < 2; ++d) {
                const int u = 2 * k + d;
                const float p = F0[v][u] + F2[v][u];
                const float m = F0[v][u] - F2[v][u];
                const float q = F1[v][u] + F3[v][u];
                const float hh = H3[v][u] - H1[v][u];
                ((float*)&s0)[d] = p + q;
                ((float*)&s2)[d] = p - q;
                ((float*)&s1)[d] = m + hh;
                ((float*)&s3)[d] = m - hh;
            }
            *(float2*)(o0 + k * 16 + c * 2) = s0;
            *(float2*)(o1 + k * 16 + c * 2) = s1;
            *(float2*)(o2 + k * 16 + c * 2) = s2;
            *(float2*)(o3 + k * 16 + c * 2) = s3;
        }
    }
}

// ---------------- launch ----------------
extern "C" void kernel_launch(void* const* d_in, const int* in_sizes, int n_in,
                              void* d_out, int out_size, void* d_ws, size_t ws_size,
                              hipStream_t stream) {
    const float* q  = (const float*)d_in[0];
    const float* wr = (const float*)d_in[3];
    const float* wi = (const float*)d_in[4];

    char* ws = (char*)d_ws;
    float2*             trig  = (float2*)(ws + 0);                  // 32 KB
    unsigned long long* score = (unsigned long long*)(ws + 32768);  // 16 KB
    int*                idx   = (int*)(ws + 49152);                 // 256 B
    float2*             Y     = (float2*)(ws + 65536);              // 4 MB

    // d_out triples as: transposed-q scratch T -> spectrum Xout (in-place) -> final output.
    float2* Xs = (float2*)d_out;

    hipMemsetAsync(score, 0, 2048 * sizeof(unsigned long long), stream);
    k_tables<<<16, 256, 0, stream>>>(trig);
    k_xpose<<<2048, 256, 0, stream>>>(q, Xs);          // (b:16, h:8, c4:16)
    k_fft<<<1024, 256, 0, stream>>>(trig, Xs, score);  // in-place T -> spectra
    k_topk<<<8, 256, 0, stream>>>(score, idx);         // 2048 candidates, 1/thread
    k_proj<<<512, 256, 0, stream>>>(Xs, wr, wi, idx, Y);
    k_synth<<<2048, 256, 0, stream>>>(Y, trig, (float*)d_out);  // (b:16, hft:8, lt:16)
}

// Round 11
// 255.902 us; speedup vs baseline: 1.1008x; 1.0705x over previous
//
#include <hip/hip_runtime.h>

// Problem constants: B=16, L=4096, H=8, E=64, K=64, F=2049 (rfft bins)
// Only bins m in [1,2048] matter (bin 0 excluded from top-k; out_ft uses slots 0..63).

#define NTHREADS 256

// LDS swizzle for the FFT working array: flips bits 1-3 by bits 4-6 (bijective, disjoint).
#define ZI(i) ((i) ^ ((((i) >> 4) & 7) << 1))

__device__ inline float2 f2add(float2 a, float2 b) { return make_float2(a.x + b.x, a.y + b.y); }
__device__ inline float2 f2sub(float2 a, float2 b) { return make_float2(a.x - b.x, a.y - b.y); }
// complex mul, exactly 4 VALU (mul, fma, mul, fma)
__device__ inline float2 cmulf(float2 a, float2 b) {
    return make_float2(__builtin_fmaf(a.x, b.x, -(a.y * b.y)),
                       __builtin_fmaf(a.x, b.y,  a.y * b.x));
}

// radix-8 DIT butterfly on 8 points (3 stages in registers).
__device__ inline void radix8(float2& u0, float2& u1, float2& u2, float2& u3,
                              float2& u4, float2& u5, float2& u6, float2& u7,
                              float2 wA, float2 wB, float2 wC) {
    float2 t1 = cmulf(wA, u1), t3 = cmulf(wA, u3), t5 = cmulf(wA, u5), t7 = cmulf(wA, u7);
    float2 a0 = f2add(u0, t1), a1 = f2sub(u0, t1);
    float2 a2 = f2add(u2, t3), a3 = f2sub(u2, t3);
    float2 a4 = f2add(u4, t5), a5 = f2sub(u4, t5);
    float2 a6 = f2add(u6, t7), a7 = f2sub(u6, t7);
    float2 s2 = cmulf(wB, a2), s3 = cmulf(wB, a3);
    float2 s6 = cmulf(wB, a6), s7 = cmulf(wB, a7);
    float2 b0 = f2add(a0, s2), b2 = f2sub(a0, s2);
    float2 b1 = make_float2(a1.x + s3.y, a1.y - s3.x);   // a1 + (-i)s3
    float2 b3 = make_float2(a1.x - s3.y, a1.y + s3.x);   // a1 - (-i)s3
    float2 b4 = f2add(a4, s6), b6 = f2sub(a4, s6);
    float2 b5 = make_float2(a5.x + s7.y, a5.y - s7.x);
    float2 b7 = make_float2(a5.x - s7.y, a5.y + s7.x);
    const float2 C8 = make_float2(0.70710678118654752f, -0.70710678118654752f);  // e^{-i pi/4}
    float2 wC1 = cmulf(wC, C8);
    float2 r4 = cmulf(wC, b4);
    float2 r5 = cmulf(wC1, b5);
    float2 r6t = cmulf(wC, b6);  float2 r6 = make_float2(r6t.y, -r6t.x);   // -i * wC * b6
    float2 r7t = cmulf(wC1, b7); float2 r7 = make_float2(r7t.y, -r7t.x);   // e^{-3i pi/4} wC b7
    u0 = f2add(b0, r4); u4 = f2sub(b0, r4);
    u1 = f2add(b1, r5); u5 = f2sub(b1, r5);
    u2 = f2add(b2, r6); u6 = f2sub(b2, r6);
    u3 = f2add(b3, r7); u7 = f2sub(b3, r7);
}

// ---------------- table kernel: trig[k] = (cos, sin)(2*pi*k/4096), f64-accurate ----------------
__global__ void k_tables(float2* __restrict__ trig) {
    int k = blockIdx.x * blockDim.x + threadIdx.x;
    if (k < 4096) {
        double th = (6.283185307179586476925286766559 * (double)k) / 4096.0;
        trig[k] = make_float2((float)cos(th), (float)sin(th));
    }
}

// ---------------- transpose + bit-reversal: q[b,l,h,e] -> T[(b,h,eo)][p][j] (float2) -----------
// 128-row tiles (33 KB LDS -> 4 blocks/CU, double the old occupancy). Block (b:16, h:8, c5:32):
// rows l = c5 + 32t (t=0..127). rev12(c5 + 32t) = rev5(c5)*128 + rev7(t): destination runs are
// contiguous 128-float2 blocks -> one wave-wide float4 store per (eo,p).
// Lane layout: j'loc = 2*lane, 2*lane+1 -> t = rev7(j'loc) = rev6(lane), rev6(lane)+64.
__global__ __launch_bounds__(256) void k_xpose(const float* __restrict__ q,
                                               float2* __restrict__ T) {
    __shared__ float tile[128][65];  // 33 KB, padded (+1)

    const int tid = threadIdx.x;
    const int bi  = blockIdx.x;
    const int b   = bi >> 8;
    const int h   = (bi >> 5) & 7;
    const int c5  = bi & 31;

    // coalesced read: 128 rows x 64 floats (16 float4 per row), 8 float4 per thread
    const float* qb = q + ((size_t)b * 4096 * 512) + (size_t)h * 64;
#pragma unroll
    for (int i = 0; i < 8; ++i) {
        const int f = tid + 256 * i;
        const int t = f >> 4, e4 = f & 15;
        const float4 v = *(const float4*)(qb + (size_t)(c5 + 32 * t) * 512 + e4 * 4);
        tile[t][e4 * 4 + 0] = v.x;
        tile[t][e4 * 4 + 1] = v.y;
        tile[t][e4 * 4 + 2] = v.z;
        tile[t][e4 * 4 + 3] = v.w;
    }
    __syncthreads();

    const int wave = tid >> 6, lane = tid & 63;
    const int rl  = __brev(lane) >> 26;  // rev6(lane): spans all 0..63 -> 2-way (free) LDS reads
    const int r5c = __brev(c5) >> 27;    // rev5(c5)
    for (int cc = wave; cc < 32; cc += 4) {
        const int eo = cc >> 2, p = cc & 3;
        const int col0 = eo * 8 + 2 * p;
        float2* dst = T + ((size_t)((b * 8 + h) * 8 + eo)) * 16384 + (size_t)p * 4096
                        + (size_t)r5c * 128;
        float4 o;
        o.x = tile[rl][col0];      o.y = tile[rl][col0 + 1];
        o.z = tile[rl + 64][col0]; o.w = tile[rl + 64][col0 + 1];
        *(float4*)(dst + 2 * lane) = o;  // 16B/lane, contiguous 1KB run per (eo,p)
    }
}

// ---------------- FFT (4 x radix-8 passes) + spectrum store + score accumulation ----------------
// Latency-oriented: eacc in registers (LDS 45.7KB -> 3 blocks/CU) and register prefetch of the
// next plane's inputs (HBM/L2 latency hides under passes 1-3 + unpack of the current plane).
__global__ __launch_bounds__(256) void k_fft(const float2* __restrict__ trig,
                                             float2* __restrict__ Xout,
                                             unsigned long long* __restrict__ score) {
    __shared__ float2 z[4096];     // 32 KB (swizzled indexing)
    __shared__ float2 ctw[1752];   // 13.7 KB: [0,24) pass1, [24,216) pass2, [216,1752) pass3

    const int tid = threadIdx.x;
    const int bi  = blockIdx.x;

    // build compact twiddle triples: ctw[off + 3j + {0,1,2}] = conj(trig[j << {sA, sA-1, sA-2}])
    for (int t = tid; t < 584; t += NTHREADS) {
        int off, j, sA;
        if (t < 8)       { off = 0;   j = t;      sA = 8; }   // pass1 (st=4,  h=8,   j<8)
        else if (t < 72) { off = 24;  j = t - 8;  sA = 5; }   // pass2 (st=7,  h=64,  j<64)
        else             { off = 216; j = t - 72; sA = 2; }   // pass3 (st=10, h=512, j<512)
        float2 a = trig[j << sA], b = trig[j << (sA - 1)], c = trig[j << (sA - 2)];
        ctw[off + 3 * j + 0] = make_float2(a.x, -a.y);
        ctw[off + 3 * j + 1] = make_float2(b.x, -b.y);
        ctw[off + 3 * j + 2] = make_float2(c.x, -c.y);
    }

    float eaccr[8];
#pragma unroll
    for (int k = 0; k < 8; ++k) eaccr[k] = 0.f;

    const float2 ONE = make_float2(1.0f, 0.0f);
    const float2* base = Xout + (size_t)bi * 16384;

    // prefetch plane 0 into registers (2 items/thread x 4 float4)
    float4 pre[2][4];
#pragma unroll
    for (int it = 0; it < 2; ++it) {
        const int t = tid + 256 * it;
#pragma unroll
        for (int g = 0; g < 4; ++g) pre[it][g] = *(const float4*)(base + 8 * t + 2 * g);
    }
    __syncthreads();  // ctw ready

    for (int p = 0; p < 4; ++p) {
        // move prefetched data to cur, then immediately issue next plane's loads
        float4 cur[2][4];
#pragma unroll
        for (int it = 0; it < 2; ++it)
#pragma unroll
            for (int g = 0; g < 4; ++g) cur[it][g] = pre[it][g];

        if (p < 3) {
            const float2* pn = base + (size_t)(p + 1) * 4096;
#pragma unroll
            for (int it = 0; it < 2; ++it) {
                const int t = tid + 256 * it;
#pragma unroll
                for (int g = 0; g < 4; ++g) pre[it][g] = *(const float4*)(pn + 8 * t + 2 * g);
            }
        }

        // pass 0 (stages 1-3, unit twiddles) on registers; store swizzled to LDS
#pragma unroll
        for (int it = 0; it < 2; ++it) {
            const int t = tid + 256 * it;
            float2 u0 = make_float2(cur[it][0].x, cur[it][0].y);
            float2 u1 = make_float2(cur[it][0].z, cur[it][0].w);
            float2 u2 = make_float2(cur[it][1].x, cur[it][1].y);
            float2 u3 = make_float2(cur[it][1].z, cur[it][1].w);
            float2 u4 = make_float2(cur[it][2].x, cur[it][2].y);
            float2 u5 = make_float2(cur[it][2].z, cur[it][2].w);
            float2 u6 = make_float2(cur[it][3].x, cur[it][3].y);
            float2 u7 = make_float2(cur[it][3].z, cur[it][3].w);
            radix8(u0, u1, u2, u3, u4, u5, u6, u7, ONE, ONE, ONE);
            const int i0 = 8 * t;
            z[ZI(i0 + 0)] = u0; z[ZI(i0 + 1)] = u1; z[ZI(i0 + 2)] = u2; z[ZI(i0 + 3)] = u3;
            z[ZI(i0 + 4)] = u4; z[ZI(i0 + 5)] = u5; z[ZI(i0 + 6)] = u6; z[ZI(i0 + 7)] = u7;
        }
        __syncthreads();

        // passes 1..3: stages (4,5,6), (7,8,9), (10,11,12); h = 8, 64, 512
#pragma unroll
        for (int p8 = 1; p8 <= 3; ++p8) {
            const int st  = 1 + 3 * p8;
            const int h   = 1 << (st - 1);
            const int off = (p8 == 1) ? 0 : (p8 == 2) ? 24 : 216;
            for (int t = tid; t < 512; t += NTHREADS) {
                const int j = t & (h - 1);
                const int g = t >> (st - 1);
                const int i0 = (g << (st + 2)) + j;
                int a0 = ZI(i0),         a1 = ZI(i0 + h),     a2 = ZI(i0 + 2 * h), a3 = ZI(i0 + 3 * h);
                int a4 = ZI(i0 + 4 * h), a5 = ZI(i0 + 5 * h), a6 = ZI(i0 + 6 * h), a7 = ZI(i0 + 7 * h);
                float2 u0 = z[a0], u1 = z[a1], u2 = z[a2], u3 = z[a3];
                float2 u4 = z[a4], u5 = z[a5], u6 = z[a6], u7 = z[a7];
                const float2 wA = ctw[off + 3 * j + 0];
                const float2 wB = ctw[off + 3 * j + 1];
                const float2 wC = ctw[off + 3 * j + 2];
                radix8(u0, u1, u2, u3, u4, u5, u6, u7, wA, wB, wC);
                z[a0] = u0; z[a1] = u1; z[a2] = u2; z[a3] = u3;
                z[a4] = u4; z[a5] = u5; z[a6] = u6; z[a7] = u7;
            }
            __syncthreads();
        }

        // unpack two real spectra; store (overwrites this pair's own plane); accumulate energy
        {
            const size_t s0 = (size_t)bi * 16384 + (size_t)p * 4096;  // = signal (bi*8+2p) * 2048
#pragma unroll
            for (int k = 0; k < 8; ++k) {
                const int t = tid + 256 * k;
                const int m = t + 1;
                float2 Za = z[ZI(m)];
                float2 Zb = z[ZI(4096 - m)];
                float Xr0 = 0.5f * (Za.x + Zb.x);
                float Xi0 = 0.5f * (Za.y - Zb.y);
                float Xr1 = 0.5f * (Za.y + Zb.y);
                float Xi1 = 0.5f * (Zb.x - Za.x);
                Xout[s0 + t]        = make_float2(Xr0, Xi0);
                Xout[s0 + 2048 + t] = make_float2(Xr1, Xi1);
                eaccr[k] += Xr0 * Xr0 + Xi0 * Xi0 + Xr1 * Xr1 + Xi1 * Xi1;
            }
        }
        __syncthreads();  // protect z before next plane's pass-0 stores
    }

    // deterministic reduction: fixed-point u64 atomics (integer adds commute exactly)
#pragma unroll
    for (int k = 0; k < 8; ++k) {
        unsigned long long v = (unsigned long long)llrintf(eaccr[k] * 1048576.0f);  // 2^20
        atomicAdd(&score[tid + 256 * k], v);
    }
}

// ---------------- top-64, parallelized: 8 blocks x 256 threads, one candidate per thread -------
__global__ __launch_bounds__(256) void k_topk(const unsigned long long* __restrict__ score,
                                              int* __restrict__ idx) {
    __shared__ unsigned long long s[2048];
    const int tid = threadIdx.x;
    for (int t = tid; t < 2048; t += 256) s[t] = score[t];
    __syncthreads();

    const int t = blockIdx.x * 256 + tid;  // 0..2047
    const unsigned long long my = s[t];
    int rank = 0;
#pragma unroll 8
    for (int u = 0; u < 2048; ++u) {
        unsigned long long o = s[u];
        rank += (int)((o > my) || (o == my && u < t));
    }
    if (rank < 64) idx[rank] = t + 1;  // store frequency index m
}

// ---------------- gather + complex projection: Y[b,j,h,f] = sum_e X[b,idx_j,h,e] * W[j,h,e,f] ----
__global__ __launch_bounds__(256) void k_proj(const float2* __restrict__ X,
                                              const float* __restrict__ wr,
                                              const float* __restrict__ wi,
                                              const int* __restrict__ idx,
                                              float2* __restrict__ Y) {
    __shared__ float2 xs[16 * 64];   // [b][e]  8 KB
    __shared__ float  wrs[64 * 64];  // [e][f] 16 KB
    __shared__ float  wis[64 * 64];  // 16 KB

    const int tid = threadIdx.x;
    const int j = blockIdx.x >> 3;
    const int h = blockIdx.x & 7;
    const int m = idx[j];

    for (int t = tid; t < 1024; t += NTHREADS) {
        int b = t >> 6, e = t & 63;
        xs[t] = X[((size_t)((b * 8 + h) * 64 + e)) * 2048 + (size_t)(m - 1)];
    }
    const float* wrb = wr + ((size_t)(j * 8 + h)) * 4096;
    const float* wib = wi + ((size_t)(j * 8 + h)) * 4096;
    for (int t = tid; t < 4096; t += NTHREADS) { wrs[t] = wrb[t]; wis[t] = wib[t]; }
    __syncthreads();

    const int b  = tid >> 4;   // 0..15
    const int fg = tid & 15;   // 0..15
    for (int fo = 0; fo < 4; ++fo) {
        int f = fg * 4 + fo;
        float yr = 0.f, yi = 0.f;
        for (int e = 0; e < 64; ++e) {
            float2 x = xs[b * 64 + e];
            float a = wrs[e * 64 + f], c = wis[e * 64 + f];
            yr = __builtin_fmaf(x.x, a, yr); yr = __builtin_fmaf(-x.y, c, yr);
            yi = __builtin_fmaf(x.x, c, yi); yi = __builtin_fmaf( x.y, a, yi);
        }
        Y[((size_t)b * 64 + j) * 512 + (size_t)(h * 64 + f)] = make_float2(yr, yi);
    }
}

// ---------------- synthesis with full w-symmetry: 1 rotator -> 4 output rows -------------------
//   out(l)      = F0+F1+F2+F3          out(l+2048) = F0-F1+F2-F3
//   out(l+1024) = (F0-F2)-(H1-H3)      out(l+3072) = (F0-F2)+(H1-H3)
__global__ __launch_bounds__(256, 2) void k_synth(const float2* __restrict__ Y,
                                                  const float2* __restrict__ trig,
                                                  float* __restrict__ out) {
    __shared__ float2 ys[64][64];  // 32 KB, pre-scaled: j=0 -> (Yr/N, 0); j>0 -> (2/N)*Y

    const int tid = threadIdx.x;
    const int bi  = blockIdx.x;
    const int b   = bi >> 7;        // 16
    const int hft = (bi >> 4) & 7;  // 8
    const int lt  = bi & 15;        // 16

    const float invN = 1.0f / 4096.0f;
    const float2* yb = Y + (size_t)b * 64 * 512 + (size_t)hft * 64;
    for (int t = tid; t < 64 * 64; t += NTHREADS) {
        int j = t >> 6, cc = t & 63;
        float2 y = yb[(size_t)j * 512 + cc];
        if (j == 0) ys[0][cc] = make_float2(y.x * invN, 0.0f);
        else        ys[j][cc] = make_float2(y.x * (2.0f * invN), y.y * (2.0f * invN));
    }
    __syncthreads();

    const int r = tid >> 3;          // 0..31
    const int c = tid & 7;           // 0..7
    const int l0 = lt * 64 + r * 2;  // base l (v=0) in [0, 1024)

    float2 rot[2], w[2];
#pragma unroll
    for (int v = 0; v < 2; ++v) {
        w[v] = trig[(l0 + v) & 4095];
        rot[v] = make_float2(1.0f, 0.0f);
    }

    float F0[2][8], F1[2][8], F2[2][8], F3[2][8], H1[2][8], H3[2][8];
#pragma unroll
    for (int v = 0; v < 2; ++v)
#pragma unroll
        for (int u = 0; u < 8; ++u) {
            F0[v][u] = F1[v][u] = F2[v][u] = F3[v][u] = 0.0f;
            H1[v][u] = H3[v][u] = 0.0f;
        }

    for (int j = 0; j < 64; j += 4) {
        // j+0 (even) -> F0
        {
            float2 yv[8];
#pragma unroll
            for (int u = 0; u < 8; ++u) yv[u] = ys[j][c * 2 + (u & 1) + (u >> 1) * 16];
#pragma unroll
            for (int v = 0; v < 2; ++v) {
                const float cx = rot[v].x, sx = rot[v].y;
#pragma unroll
                for (int u = 0; u < 8; ++u) {
                    float a = F0[v][u];
                    a = __builtin_fmaf(cx, yv[u].x, a);
                    a = __builtin_fmaf(-sx, yv[u].y, a);
                    F0[v][u] = a;
                }
                float nx = __builtin_fmaf(rot[v].x, w[v].x, -(rot[v].y * w[v].y));
                float ny = __builtin_fmaf(rot[v].x, w[v].y,  (rot[v].y * w[v].x));
                rot[v] = make_float2(nx, ny);
            }
        }
        // j+1 (odd) -> F1, H1
        {
            float2 yv[8];
#pragma unroll
            for (int u = 0; u < 8; ++u) yv[u] = ys[j + 1][c * 2 + (u & 1) + (u >> 1) * 16];
#pragma unroll
            for (int v = 0; v < 2; ++v) {
                const float cx = rot[v].x, sx = rot[v].y;
#pragma unroll
                for (int u = 0; u < 8; ++u) {
                    float a = F1[v][u], g = H1[v][u];
                    a = __builtin_fmaf(cx, yv[u].x, a);
                    a = __builtin_fmaf(-sx, yv[u].y, a);
                    g = __builtin_fmaf(sx, yv[u].x, g);
                    g = __builtin_fmaf(cx, yv[u].y, g);
                    F1[v][u] = a; H1[v][u] = g;
                }
                float nx = __builtin_fmaf(rot[v].x, w[v].x, -(rot[v].y * w[v].y));
                float ny = __builtin_fmaf(rot[v].x, w[v].y,  (rot[v].y * w[v].x));
                rot[v] = make_float2(nx, ny);
            }
        }
        // j+2 (even) -> F2
        {
            float2 yv[8];
#pragma unroll
            for (int u = 0; u < 8; ++u) yv[u] = ys[j + 2][c * 2 + (u & 1) + (u >> 1) * 16];
#pragma unroll
            for (int v = 0; v < 2; ++v) {
                const float cx = rot[v].x, sx = rot[v].y;
#pragma unroll
                for (int u = 0; u < 8; ++u) {
                    float a = F2[v][u];
                    a = __builtin_fmaf(cx, yv[u].x, a);
                    a = __builtin_fmaf(-sx, yv[u].y, a);
                    F2[v][u] = a;
                }
                float nx = __builtin_fmaf(rot[v].x, w[v].x, -(rot[v].y * w[v].y));
                float ny = __builtin_fmaf(rot[v].x, w[v].y,  (rot[v].y * w[v].x));
                rot[v] = make_float2(nx, ny);
            }
        }
        // j+3 (odd) -> F3, H3
        {
            float2 yv[8];
#pragma unroll
            for (int u = 0; u < 8; ++u) yv[u] = ys[j + 3][c * 2 + (u & 1) + (u >> 1) * 16];
#pragma unroll
            for (int v = 0; v < 2; ++v) {
                const float cx = rot[v].x, sx = rot[v].y;
#pragma unroll
                for (int u = 0; u < 8; ++u) {
                    float a = F3[v][u], g = H3[v][u];
                    a = __builtin_fmaf(cx, yv[u].x, a);
                    a = __builtin_fmaf(-sx, yv[u].y, a);
                    g = __builtin_fmaf(sx, yv[u].x, g);
                    g = __builtin_fmaf(cx, yv[u].y, g);
                    F3[v][u] = a; H3[v][u] = g;
                }
                float nx = __builtin_fmaf(rot[v].x, w[v].x, -(rot[v].y * w[v].y));
                float ny = __builtin_fmaf(rot[v].x, w[v].y,  (rot[v].y * w[v].x));
                rot[v] = make_float2(nx, ny);
            }
        }
    }

    // stores: 4 rows per (v): l0+v, +1024, +2048, +3072
#pragma unroll
    for (int v = 0; v < 2; ++v) {
        float* o0 = out + ((size_t)(b * 4096 + l0 + v)) * 512 + (size_t)hft * 64;
        float* o1 = o0 + (size_t)1024 * 512;
        float* o2 = o0 + (size_t)2048 * 512;
        float* o3 = o0 + (size_t)3072 * 512;
#pragma unroll
        for (int k = 0; k < 4; ++k) {
            float2 s0, s1, s2, s3;
#pragma unroll
            for (int d = 0; d < 2; ++d) {
                const int u = 2 * k + d;
                const float p = F0[v][u] + F2[v][u];
                const float m = F0[v][u] - F2[v][u];
                const float q = F1[v][u] + F3[v][u];
                const float hh = H3[v][u] - H1[v][u];
                ((float*)&s0)[d] = p + q;
                ((float*)&s2)[d] = p - q;
                ((float*)&s1)[d] = m + hh;
                ((float*)&s3)[d] = m - hh;
            }
            *(float2*)(o0 + k * 16 + c * 2) = s0;
            *(float2*)(o1 + k * 16 + c * 2) = s1;
            *(float2*)(o2 + k * 16 + c * 2) = s2;
            *(float2*)(o3 + k * 16 + c * 2) = s3;
        }
    }
}

// ---------------- launch ----------------
extern "C" void kernel_launch(void* const* d_in, const int* in_sizes, int n_in,
                              void* d_out, int out_size, void* d_ws, size_t ws_size,
                              hipStream_t stream) {
    const float* q  = (const float*)d_in[0];
    const float* wr = (const float*)d_in[3];
    const float* wi = (const float*)d_in[4];

    char* ws = (char*)d_ws;
    float2*             trig  = (float2*)(ws + 0);                  // 32 KB
    unsigned long long* score = (unsigned long long*)(ws + 32768);  // 16 KB
    int*                idx   = (int*)(ws + 49152);                 // 256 B
    float2*             Y     = (float2*)(ws + 65536);              // 4 MB

    // d_out triples as: transposed-q scratch T -> spectrum Xout (in-place) -> final output.
    float2* Xs = (float2*)d_out;

    hipMemsetAsync(score, 0, 2048 * sizeof(unsigned long long), stream);
    k_tables<<<16, 256, 0, stream>>>(trig);
    k_xpose<<<4096, 256, 0, stream>>>(q, Xs);          // (b:16, h:8, c5:32), 128-row tiles
    k_fft<<<1024, 256, 0, stream>>>(trig, Xs, score);  // in-place T -> spectra
    k_topk<<<8, 256, 0, stream>>>(score, idx);         // 2048 candidates, 1/thread
    k_proj<<<512, 256, 0, stream>>>(Xs, wr, wi, idx, Y);
    k_synth<<<2048, 256, 0, stream>>>(Y, trig, (float*)d_out);  // (b:16, hft:8, lt:16)
}